// Round 1
// baseline (983.553 us; speedup 1.0000x reference)
//
#include <hip/hip_runtime.h>

#define FDIM 64

// XW[r][n][f] = sum_k X[n][k] * W[r][k][f]
// block = 256 threads: 16 nodes (nl = tid>>4) x 16 float4 feature groups (fq = tid&15)
// W_r staged in LDS as [64 k][16 float4].
__global__ __launch_bounds__(256) void xw_gemm(
    const float* __restrict__ X, const float* __restrict__ Wmat,
    float* __restrict__ XW, int rbase, int N)
{
    const int r = rbase + blockIdx.y;
    __shared__ float4 Wl[1024];  // 64 x 16 float4 = 16 KB
    const float4* Wg = (const float4*)(Wmat + (size_t)r * FDIM * FDIM);
    const int tid = threadIdx.x;
#pragma unroll
    for (int i = 0; i < 4; ++i) Wl[tid + i * 256] = Wg[tid + i * 256];
    __syncthreads();

    const int fq = tid & 15;
    const int nl = tid >> 4;
    const int n  = blockIdx.x * 16 + nl;
    if (n >= N) return;

    const float4* Xr = (const float4*)(X + (size_t)n * FDIM);
    float4 acc = make_float4(0.f, 0.f, 0.f, 0.f);
#pragma unroll
    for (int k4 = 0; k4 < 16; ++k4) {
        const float4 x  = Xr[k4];
        const float4 w0 = Wl[(k4 * 4 + 0) * 16 + fq];
        const float4 w1 = Wl[(k4 * 4 + 1) * 16 + fq];
        const float4 w2 = Wl[(k4 * 4 + 2) * 16 + fq];
        const float4 w3 = Wl[(k4 * 4 + 3) * 16 + fq];
        acc.x += x.x * w0.x + x.y * w1.x + x.z * w2.x + x.w * w3.x;
        acc.y += x.x * w0.y + x.y * w1.y + x.z * w2.y + x.w * w3.y;
        acc.z += x.x * w0.z + x.y * w1.z + x.z * w2.z + x.w * w3.z;
        acc.w += x.x * w0.w + x.y * w1.w + x.z * w2.w + x.w * w3.w;
    }
    float4* out = (float4*)(XW + (size_t)blockIdx.y * N * FDIM + (size_t)n * FDIM);
    out[fq] = acc;
}

// One wave per edge; lane = output feature. Gather XW row (coalesced 256B),
// scale by A[e], atomicAdd into Y[dst].
// relFilter >= 0: XW holds only relation relFilter ([N][64]); skip other edges.
// relFilter <  0: XW holds all relations ([R][N][64]); row = etype*N + src.
__global__ __launch_bounds__(256) void edge_scatter(
    const float* __restrict__ XW, const int* __restrict__ src,
    const int* __restrict__ dst, const int* __restrict__ etype,
    const float* __restrict__ A, float* __restrict__ Y,
    int E, int relFilter, int N)
{
    const int e = blockIdx.x * 4 + (threadIdx.x >> 6);
    if (e >= E) return;
    const int lane = threadIdx.x & 63;
    const int et = etype[e];
    size_t row;
    if (relFilter >= 0) {
        if (et != relFilter) return;
        row = (size_t)src[e];
    } else {
        row = (size_t)et * N + (size_t)src[e];
    }
    const float a = A[e];
    const float v = XW[row * FDIM + lane] * a;
    atomicAdd(Y + (size_t)dst[e] * FDIM + lane, v);
}

extern "C" void kernel_launch(void* const* d_in, const int* in_sizes, int n_in,
                              void* d_out, int out_size, void* d_ws, size_t ws_size,
                              hipStream_t stream)
{
    const float* X     = (const float*)d_in[0];
    const float* Wmat  = (const float*)d_in[1];
    const float* A     = (const float*)d_in[2];
    const int*   src   = (const int*)d_in[3];
    const int*   dst   = (const int*)d_in[4];
    const int*   etype = (const int*)d_in[5];
    float* Y = (float*)d_out;

    const int N = in_sizes[0] / FDIM;            // 100000
    const int R = in_sizes[1] / (FDIM * FDIM);   // 8
    const int E = in_sizes[2];                   // 3200000

    // d_out is poisoned 0xAA before every timed call — zero it.
    hipMemsetAsync(d_out, 0, (size_t)N * FDIM * sizeof(float), stream);

    float* XW = (float*)d_ws;
    const size_t needFull = (size_t)R * N * FDIM * sizeof(float);  // 204.8 MB
    const int scatterBlocks = (E + 3) / 4;

    if (ws_size >= needFull) {
        // Path A: materialize all relations, single scatter pass.
        dim3 g((N + 15) / 16, R);
        xw_gemm<<<g, 256, 0, stream>>>(X, Wmat, XW, 0, N);
        edge_scatter<<<scatterBlocks, 256, 0, stream>>>(
            XW, src, dst, etype, A, Y, E, -1, N);
    } else {
        // Path B: per-relation loop, 25.6 MB XW buffer, filtered scatter.
        for (int r = 0; r < R; ++r) {
            dim3 g((N + 15) / 16, 1);
            xw_gemm<<<g, 256, 0, stream>>>(X, Wmat, XW, r, N);
            edge_scatter<<<scatterBlocks, 256, 0, stream>>>(
                XW, src, dst, etype, A, Y, E, r, N);
        }
    }
}

// Round 2
// 903.615 us; speedup vs baseline: 1.0885x; 1.0885x over previous
//
#include <hip/hip_runtime.h>

#define FDIM 64

// XW[r][n][f] = sum_k X[n][k] * W[r][k][f]
// block = 256 threads: 16 nodes x 16 float4-feature-groups; loops ALL relations
// in-block so X is read from global exactly once (staged in LDS).
__global__ __launch_bounds__(256) void xw_gemm(
    const float* __restrict__ X, const float* __restrict__ Wmat,
    float* __restrict__ XW, int N, int R)
{
    __shared__ float4 Wl[1024];    // 64 k x 16 fq  (16 KB)
    __shared__ float4 Xl[256];     // 16 nodes x 16 k4 (4 KB)
    const int tid = threadIdx.x;
    const int fq = tid & 15;
    const int nl = tid >> 4;
    const int nbase = blockIdx.x * 16;

    // Stage X tile: thread tid loads node nbase+(tid>>4), float4 (tid&15).
    {
        const int n = nbase + nl;
        Xl[tid] = (n < N) ? ((const float4*)(X + (size_t)n * FDIM))[fq]
                          : make_float4(0.f, 0.f, 0.f, 0.f);
    }

    const int n = nbase + nl;
    for (int r = 0; r < R; ++r) {
        __syncthreads();  // protect Wl from previous iteration's readers
        const float4* Wg = (const float4*)(Wmat + (size_t)r * FDIM * FDIM);
#pragma unroll
        for (int i = 0; i < 4; ++i) Wl[tid + i * 256] = Wg[tid + i * 256];
        __syncthreads();

        float4 acc = make_float4(0.f, 0.f, 0.f, 0.f);
#pragma unroll
        for (int k4 = 0; k4 < 16; ++k4) {
            const float4 x  = Xl[nl * 16 + k4];
            const float4 w0 = Wl[(k4 * 4 + 0) * 16 + fq];
            const float4 w1 = Wl[(k4 * 4 + 1) * 16 + fq];
            const float4 w2 = Wl[(k4 * 4 + 2) * 16 + fq];
            const float4 w3 = Wl[(k4 * 4 + 3) * 16 + fq];
            acc.x += x.x * w0.x + x.y * w1.x + x.z * w2.x + x.w * w3.x;
            acc.y += x.x * w0.y + x.y * w1.y + x.z * w2.y + x.w * w3.y;
            acc.z += x.x * w0.z + x.y * w1.z + x.z * w2.z + x.w * w3.z;
            acc.w += x.x * w0.w + x.y * w1.w + x.z * w2.w + x.w * w3.w;
        }
        if (n < N) {
            float4* out = (float4*)(XW + ((size_t)r * N + n) * FDIM);
            out[fq] = acc;
        }
    }
}

// Grid-stride persistent waves. Each wave grabs a chunk of 64 edges:
// lane l vector-loads edge (chunk*64+l)'s metadata (fully coalesced), then the
// wave processes the 64 edges via __shfl broadcast, 8 gathers in flight at a
// time (MLP=8/wave). lane = feature -> 256B coalesced gather + atomic rows.
__global__ __launch_bounds__(256) void edge_scatter(
    const float* __restrict__ XW, const int* __restrict__ src,
    const int* __restrict__ dst, const int* __restrict__ etype,
    const float* __restrict__ A, float* __restrict__ Y,
    int E, int N, int nChunks)
{
    const int lane = threadIdx.x & 63;
    const int waveId = (int)((blockIdx.x * blockDim.x + threadIdx.x) >> 6);
    const int nWaves = (int)((gridDim.x * blockDim.x) >> 6);

    for (int c = waveId; c < nChunks; c += nWaves) {
        const int e0 = c * 64 + lane;
        const bool valid = (e0 < E);
        const int   s = valid ? src[e0]   : 0;
        const int   d = valid ? dst[e0]   : 0;
        const int   t = valid ? etype[e0] : 0;
        const float a = valid ? A[e0]     : 0.0f;   // a=0 => exact no-op add

#pragma unroll
        for (int jb = 0; jb < 8; ++jb) {
            float v[8];
            int   dd[8];
            float aa[8];
#pragma unroll
            for (int u = 0; u < 8; ++u) {
                const int j = jb * 8 + u;
                const int      sj  = __shfl(s, j, 64);
                const int      tj  = __shfl(t, j, 64);
                dd[u] = __shfl(d, j, 64);
                aa[u] = __shfl(a, j, 64);
                const unsigned off = ((unsigned)tj * (unsigned)N + (unsigned)sj) * FDIM + lane;
                v[u] = XW[off];                      // 8 independent gathers in flight
            }
#pragma unroll
            for (int u = 0; u < 8; ++u) {
                atomicAdd(Y + (unsigned)dd[u] * FDIM + lane, v[u] * aa[u]);
            }
        }
    }
}

extern "C" void kernel_launch(void* const* d_in, const int* in_sizes, int n_in,
                              void* d_out, int out_size, void* d_ws, size_t ws_size,
                              hipStream_t stream)
{
    const float* X     = (const float*)d_in[0];
    const float* Wmat  = (const float*)d_in[1];
    const float* A     = (const float*)d_in[2];
    const int*   src   = (const int*)d_in[3];
    const int*   dst   = (const int*)d_in[4];
    const int*   etype = (const int*)d_in[5];
    float* Y = (float*)d_out;

    const int N = in_sizes[0] / FDIM;            // 100000
    const int R = in_sizes[1] / (FDIM * FDIM);   // 8
    const int E = in_sizes[2];                   // 3200000

    hipMemsetAsync(d_out, 0, (size_t)out_size * sizeof(float), stream);

    float* XW = (float*)d_ws;
    xw_gemm<<<(N + 15) / 16, 256, 0, stream>>>(X, Wmat, XW, N, R);

    const int nChunks = (E + 63) / 64;
    edge_scatter<<<2048, 256, 0, stream>>>(XW, src, dst, etype, A, Y, E, N, nChunks);
}